// Round 1
// 1291.425 us; speedup vs baseline: 1.0463x; 1.0463x over previous
//
#include <hip/hip_runtime.h>

typedef __bf16 bf16;
typedef __bf16 bf16x8 __attribute__((ext_vector_type(8)));
typedef float f32x4 __attribute__((ext_vector_type(4)));

#define NJ 24
#define CIN_ 32
#define COUT_ 32
#define KT 15
#define PAD_ 7
#define NB 32
#define T_ 4096
#define NG 12           // pooled groups
#define KC 128          // 4 neighbor joints * 32 cin
#define TT 128          // t-tile per block
#define ROWS (TT + KT - 1)      // 142 rows used by compute
#define ROWS_ST 144             // rows staged: 36 x (1KB = 4 rows)
#define PITCH 136               // fallback-kernel LDS pitch (bf16)
#define TPF 8                   // front zero-pad rows in xT
#define TROWS (TPF + T_ + 16)   // 4120 padded rows per batch
#define XROW_B (NJ * CIN_ * 2)  // 1536 B per xT row
#define XT_OFFSET ((size_t)2 << 20)

// ---------------------------------------------------------------------------
// Weight prep (unchanged): pooled, masked, bf16 weights
// Wp[((g*15 + tap)*32 + cout)*128 + nj*32 + cin]
// ---------------------------------------------------------------------------
__global__ __launch_bounds__(256) void wprep(const float* __restrict__ W,
                                             bf16* __restrict__ Wp) {
    int idx = blockIdx.x * 256 + threadIdx.x;
    int cin_f = idx & 127;
    int cout  = (idx >> 7) & 31;
    int gt    = idx >> 12;
    int tap   = gt % 15;
    int g     = gt / 15;
    int nj    = cin_f >> 5;
    int cin   = cin_f & 31;
    int i     = 2 * g - 1 + nj;
    int j0 = 2 * g, j1 = 2 * g + 1;
    const int so = NJ * CIN_ * KT;
    float v = 0.f;
    if (nj == 0) {
        if (i >= 0) v = W[(j0 * 32 + cout) * so + (i * 32 + cin) * 15 + tap];
    } else if (nj == 3) {
        if (i < NJ) v = W[(j1 * 32 + cout) * so + (i * 32 + cin) * 15 + tap];
    } else {
        v = W[(j0 * 32 + cout) * so + (i * 32 + cin) * 15 + tap]
          + W[(j1 * 32 + cout) * so + (i * 32 + cin) * 15 + tap];
    }
    Wp[idx] = (bf16)(0.5f * v);
}

// ---------------------------------------------------------------------------
// xpad: zero the halo rows of xT (rows 0..7 and 4104..4119 per batch)
// ---------------------------------------------------------------------------
__global__ __launch_bounds__(256) void xpad(bf16* __restrict__ xT) {
    int idx = blockIdx.x * 256 + threadIdx.x;  // 32 b * 24 rows * 96 chunks
    int b   = idx / 2304;
    int rr  = idx % 2304;
    int row = rr / 96;
    int c16 = rr % 96;
    int rg  = (row < TPF) ? row : (T_ + row);  // 0..7 or 4104..4119
    f32x4 z = {};
    *(f32x4*)((char*)xT + ((size_t)b * TROWS + rg) * XROW_B + c16 * 16) = z;
}

// ---------------------------------------------------------------------------
// xprep: transpose+convert x[b][c][t] fp32 -> xT[b][TPF+t][c] bf16
// block: 128 t x 64 c tile; grid (32 tblk, 12 cblk, 32 b)
// ---------------------------------------------------------------------------
__global__ __launch_bounds__(256) void xprep(const float* __restrict__ x,
                                             bf16* __restrict__ xT) {
    __shared__ __align__(16) bf16 tile[128 * 72];   // pitch 72 (rows 144 B)
    const int tid = threadIdx.x;
    const int tb  = blockIdx.x;
    const int cb  = blockIdx.y;
    const int b   = blockIdx.z;

    const float* xb = x + (size_t)b * (NJ * CIN_) * T_
                        + (size_t)(cb * 64) * T_ + tb * 128;
    int t4 = tid & 31, cl = tid >> 5;               // 32 t4-chunks x 8 c
    #pragma unroll
    for (int p = 0; p < 8; ++p) {
        int c = p * 8 + cl;
        f32x4 v = *(const f32x4*)(xb + (size_t)c * T_ + t4 * 4);
        #pragma unroll
        for (int j = 0; j < 4; ++j)
            tile[(t4 * 4 + j) * 72 + c] = (bf16)v[j];
    }
    __syncthreads();

    int c8 = tid & 7, tl = tid >> 3;                // 32 t x 8 chunks of 8c
    bf16* dst = xT + ((size_t)b * TROWS + TPF + (size_t)tb * 128) * (NJ * CIN_)
                   + cb * 64;
    #pragma unroll
    for (int p = 0; p < 4; ++p) {
        int t = p * 32 + tl;
        *(bf16x8*)(dst + (size_t)t * (NJ * CIN_) + c8 * 8) =
            *(const bf16x8*)(tile + t * 72 + c8 * 8);
    }
}

// ---------------------------------------------------------------------------
// skconv2: conv(Wp) + bias-pool + LeakyReLU, reading transposed bf16 xT.
// Staging: 36x global_load_lds dwordx4 into linear [144][128] LDS rows,
// XOR chunk-swizzle (chunk ^ (row&7)) applied on the global SOURCE address
// and again on the LDS read side (same involution -> conflict-free-ish).
// ---------------------------------------------------------------------------
__global__ __launch_bounds__(256, 4) void skconv2(const bf16* __restrict__ xT,
                                                  const bf16* __restrict__ Wp,
                                                  const float* __restrict__ bias,
                                                  float* __restrict__ out) {
    __shared__ __align__(16) bf16 xs[ROWS_ST * 128];

    const int tid  = threadIdx.x;
    const int lane = tid & 63;
    const int wave = tid >> 6;
    const int t0   = blockIdx.x * TT;
    const int g    = blockIdx.y;
    const int b    = blockIdx.z;

    // ---- stage: 9 global_load_lds per wave, 4 rows (1 KB) each
    {
        const char* srcbase = (const char*)xT
            + ((size_t)b * TROWS + (size_t)(t0 + 1)) * XROW_B   // t_pad = t0-7+TPF+row
            + (long)(2 * g - 1) * 64;                           // channel window
        const int lr = lane >> 4;       // row within 4-row chunk
        const int lc = lane & 15;       // dest 16B chunk within row
        #pragma unroll
        for (int j = 0; j < 9; ++j) {
            int i    = wave * 9 + j;
            int row  = 4 * i + lr;
            int chnk = lc ^ (row & 7);  // pre-swizzled source
            const char* src = srcbase + (size_t)row * XROW_B + chnk * 16;
            __builtin_amdgcn_global_load_lds(
                (const __attribute__((address_space(1))) void*)src,
                (__attribute__((address_space(3))) void*)(xs + i * 512),
                16, 0, 0);
        }
    }
    __syncthreads();

    const int r    = lane & 15;
    const int q    = lane >> 4;
    const int woff = wave * 32;
    const int qo   = q * 8;

    f32x4 acc[2][2] = {};
    const bf16* wr = Wp + (size_t)g * (KT * 32 * 128) + r * 128 + qo;

    #pragma unroll
    for (int k = 0; k < KT; ++k) {
        const bf16* wk = wr + k * 4096;
        const int row0 = woff + r + k;          // <= 125; row1 <= 141
        const int sw   = row0 & 7;              // (row0+16)&7 == sw
        const bf16* x0 = xs + row0 * 128;
        const bf16* x1 = x0 + 16 * 128;
        #pragma unroll
        for (int cc = 0; cc < 4; ++cc) {
            int ch = ((q + 4 * cc) ^ sw) * 8;   // swizzled 8-elem chunk
            bf16x8 a0 = *(const bf16x8*)(wk + cc * 32);
            bf16x8 a1 = *(const bf16x8*)(wk + 2048 + cc * 32);
            bf16x8 b0 = *(const bf16x8*)(x0 + ch);
            bf16x8 b1 = *(const bf16x8*)(x1 + ch);
            acc[0][0] = __builtin_amdgcn_mfma_f32_16x16x32_bf16(a0, b0, acc[0][0], 0, 0, 0);
            acc[0][1] = __builtin_amdgcn_mfma_f32_16x16x32_bf16(a0, b1, acc[0][1], 0, 0, 0);
            acc[1][0] = __builtin_amdgcn_mfma_f32_16x16x32_bf16(a1, b0, acc[1][0], 0, 0, 0);
            acc[1][1] = __builtin_amdgcn_mfma_f32_16x16x32_bf16(a1, b1, acc[1][1], 0, 0, 0);
        }
    }

    // ---- epilogue: pooled bias + LeakyReLU(0.2), store fp32
    float* ob = out + (size_t)b * (NG * COUT_) * T_;
    #pragma unroll
    for (int mt = 0; mt < 2; ++mt) {
        #pragma unroll
        for (int reg = 0; reg < 4; ++reg) {
            int cout = mt * 16 + q * 4 + reg;
            float bp = 0.5f * (bias[(2 * g) * 32 + cout] +
                               bias[(2 * g + 1) * 32 + cout]);
            #pragma unroll
            for (int nt = 0; nt < 2; ++nt) {
                float v = acc[mt][nt][reg] + bp;
                v = (v >= 0.f) ? v : 0.2f * v;
                ob[(size_t)(g * COUT_ + cout) * T_ + (t0 + woff + nt * 16 + r)] = v;
            }
        }
    }
}

// ---------------------------------------------------------------------------
// Fallback (proven current kernel) if workspace is too small for xT
// ---------------------------------------------------------------------------
__global__ __launch_bounds__(256) void skconv_fb(const float* __restrict__ x,
                                                 const bf16* __restrict__ Wp,
                                                 const float* __restrict__ bias,
                                                 float* __restrict__ out) {
    __shared__ __align__(16) bf16 xs[ROWS * PITCH];

    const int tid = threadIdx.x;
    const int t0  = blockIdx.x * TT;
    const int g   = blockIdx.y;
    const int b   = blockIdx.z;

    const int cbase = (2 * g - 1) * 32;
    const float* xb = x + (size_t)b * (NJ * CIN_) * T_;
    #pragma unroll
    for (int it = 0; it < (KC * ROWS) / 256; ++it) {
        int idx = tid + it * 256;
        int c   = idx / ROWS;
        int tl  = idx - c * ROWS;
        int gtt = t0 - PAD_ + tl;
        int gc  = cbase + c;
        float v = 0.f;
        if (gtt >= 0 && gtt < T_ && gc >= 0 && gc < NJ * CIN_)
            v = xb[gc * T_ + gtt];
        xs[tl * PITCH + c] = (bf16)v;
    }
    __syncthreads();

    const int lane = tid & 63;
    const int wave = tid >> 6;
    const int r    = lane & 15;
    const int q    = lane >> 4;
    const int woff = wave * 32;
    const int qo   = q * 8;

    f32x4 acc[2][2] = {};
    const bf16* wg = Wp + (size_t)g * (KT * 32 * 128);
    for (int k = 0; k < KT; ++k) {
        const bf16* wr0   = wg + k * (32 * 128) + r * 128 + qo;
        const bf16* wr1   = wr0 + 16 * 128;
        const bf16* xrow0 = xs + (woff + r + k) * PITCH + qo;
        const bf16* xrow1 = xrow0 + 16 * PITCH;
        #pragma unroll
        for (int cc = 0; cc < 4; ++cc) {
            bf16x8 a0 = *(const bf16x8*)(wr0 + cc * 32);
            bf16x8 a1 = *(const bf16x8*)(wr1 + cc * 32);
            bf16x8 b0 = *(const bf16x8*)(xrow0 + cc * 32);
            bf16x8 b1 = *(const bf16x8*)(xrow1 + cc * 32);
            acc[0][0] = __builtin_amdgcn_mfma_f32_16x16x32_bf16(a0, b0, acc[0][0], 0, 0, 0);
            acc[0][1] = __builtin_amdgcn_mfma_f32_16x16x32_bf16(a0, b1, acc[0][1], 0, 0, 0);
            acc[1][0] = __builtin_amdgcn_mfma_f32_16x16x32_bf16(a1, b0, acc[1][0], 0, 0, 0);
            acc[1][1] = __builtin_amdgcn_mfma_f32_16x16x32_bf16(a1, b1, acc[1][1], 0, 0, 0);
        }
    }

    float* ob = out + (size_t)b * (NG * COUT_) * T_;
    #pragma unroll
    for (int mt = 0; mt < 2; ++mt) {
        #pragma unroll
        for (int reg = 0; reg < 4; ++reg) {
            int cout = mt * 16 + q * 4 + reg;
            float bp = 0.5f * (bias[(2 * g) * 32 + cout] +
                               bias[(2 * g + 1) * 32 + cout]);
            #pragma unroll
            for (int nt = 0; nt < 2; ++nt) {
                float v = acc[mt][nt][reg] + bp;
                v = (v >= 0.f) ? v : 0.2f * v;
                ob[(size_t)(g * COUT_ + cout) * T_ + (t0 + woff + nt * 16 + r)] = v;
            }
        }
    }
}

// ---------------------------------------------------------------------------
extern "C" void kernel_launch(void* const* d_in, const int* in_sizes, int n_in,
                              void* d_out, int out_size, void* d_ws, size_t ws_size,
                              hipStream_t stream) {
    (void)in_sizes; (void)n_in; (void)out_size;
    const float* x    = (const float*)d_in[0];
    const float* W    = (const float*)d_in[1];
    const float* bias = (const float*)d_in[2];
    bf16* Wp   = (bf16*)d_ws;                         // 1.47 MB at offset 0
    float* out = (float*)d_out;

    wprep<<<dim3((NG * KT * 32 * 128) / 256), dim3(256), 0, stream>>>(W, Wp);

    const size_t xt_bytes = (size_t)NB * TROWS * (NJ * CIN_) * 2;  // ~202.5 MB
    if (ws_size >= XT_OFFSET + xt_bytes + 4096) {
        bf16* xT = (bf16*)((char*)d_ws + XT_OFFSET);
        xpad<<<dim3(288), dim3(256), 0, stream>>>(xT);
        xprep<<<dim3(T_ / 128, NG, NB), dim3(256), 0, stream>>>(x, xT);
        skconv2<<<dim3(T_ / TT, NG, NB), dim3(256), 0, stream>>>(xT, Wp, bias, out);
    } else {
        skconv_fb<<<dim3(T_ / TT, NG, NB), dim3(256), 0, stream>>>(x, Wp, bias, out);
    }
}

// Round 2
// 843.174 us; speedup vs baseline: 1.6026x; 1.5316x over previous
//
#include <hip/hip_runtime.h>

typedef __bf16 bf16;
typedef __bf16 bf16x8 __attribute__((ext_vector_type(8)));
typedef float f32x4 __attribute__((ext_vector_type(4)));

#define NJ 24
#define CIN_ 32
#define COUT_ 32
#define KT 15
#define PAD_ 7
#define NB 32
#define T_ 4096
#define NG 12           // pooled groups
#define KC 128          // 4 neighbor joints * 32 cin
#define TT 128          // t-tile per block
#define ROWS (TT + KT - 1)      // 142 rows used by compute
#define ROWS_ST 144             // rows staged: 36 x (1KB = 4 rows)
#define PITCH 136               // fallback-kernel LDS pitch (bf16)
#define TPF 8                   // front zero-pad rows in xT
#define TROWS (TPF + T_ + 16)   // 4120 padded rows per batch
#define XROW_B (NJ * CIN_ * 2)  // 1536 B per xT row
#define XT_OFFSET ((size_t)2 << 20)
#define WTAP_B (32 * 128 * 2)   // 8192 B of weights per (g,tap)

// ---------------------------------------------------------------------------
// Weight prep: pooled, masked, bf16 weights.
// swz=1: bake XOR bank-swizzle into the 16B-chunk index (c ^= cout&7) so the
// LDS copy can be linear and A-fragment ds_read_b128 is ~conflict-free.
// ---------------------------------------------------------------------------
__global__ __launch_bounds__(256) void wprep(const float* __restrict__ W,
                                             bf16* __restrict__ Wp, int swz) {
    int idx = blockIdx.x * 256 + threadIdx.x;
    int cin_f = idx & 127;
    int cout  = (idx >> 7) & 31;
    int gt    = idx >> 12;
    int tap   = gt % 15;
    int g     = gt / 15;
    int nj    = cin_f >> 5;
    int cin   = cin_f & 31;
    int i     = 2 * g - 1 + nj;
    int j0 = 2 * g, j1 = 2 * g + 1;
    const int so = NJ * CIN_ * KT;
    float v = 0.f;
    if (nj == 0) {
        if (i >= 0) v = W[(j0 * 32 + cout) * so + (i * 32 + cin) * 15 + tap];
    } else if (nj == 3) {
        if (i < NJ) v = W[(j1 * 32 + cout) * so + (i * 32 + cin) * 15 + tap];
    } else {
        v = W[(j0 * 32 + cout) * so + (i * 32 + cin) * 15 + tap]
          + W[(j1 * 32 + cout) * so + (i * 32 + cin) * 15 + tap];
    }
    int c = cin_f >> 3, e = cin_f & 7;
    int cs = swz ? (c ^ (cout & 7)) : c;
    Wp[(idx & ~127) + cs * 8 + e] = (bf16)(0.5f * v);
}

// ---------------------------------------------------------------------------
// xpad: zero halo rows of xT + small guard regions before/after the array
// (g=0 window under-reads 64B before row start; keep it NaN-free).
// ---------------------------------------------------------------------------
__global__ __launch_bounds__(256) void xpad(bf16* __restrict__ xT) {
    f32x4 z = {};
    if (blockIdx.x == 288) {
        if (threadIdx.x < 16)
            *(f32x4*)((char*)xT - 256 + threadIdx.x * 16) = z;
        else if (threadIdx.x < 32)
            *(f32x4*)((char*)xT + (size_t)NB * TROWS * XROW_B +
                      (threadIdx.x - 16) * 16) = z;
        return;
    }
    int idx = blockIdx.x * 256 + threadIdx.x;  // 32 b * 24 rows * 96 chunks
    int b   = idx / 2304;
    int rr  = idx % 2304;
    int row = rr / 96;
    int c16 = rr % 96;
    int rg  = (row < TPF) ? row : (T_ + row);  // 0..7 or 4104..4119
    *(f32x4*)((char*)xT + ((size_t)b * TROWS + rg) * XROW_B + c16 * 16) = z;
}

// ---------------------------------------------------------------------------
// xprep: transpose+convert x[b][c][t] fp32 -> xT[b][TPF+t][c] bf16 (linear)
// ---------------------------------------------------------------------------
__global__ __launch_bounds__(256) void xprep(const float* __restrict__ x,
                                             bf16* __restrict__ xT) {
    __shared__ __align__(16) bf16 tile[128 * 72];   // pitch 72 (rows 144 B)
    const int tid = threadIdx.x;
    const int tb  = blockIdx.x;
    const int cb  = blockIdx.y;
    const int b   = blockIdx.z;

    const float* xb = x + (size_t)b * (NJ * CIN_) * T_
                        + (size_t)(cb * 64) * T_ + tb * 128;
    int t4 = tid & 31, cl = tid >> 5;               // 32 t4-chunks x 8 c
    #pragma unroll
    for (int p = 0; p < 8; ++p) {
        int c = p * 8 + cl;
        f32x4 v = *(const f32x4*)(xb + (size_t)c * T_ + t4 * 4);
        #pragma unroll
        for (int j = 0; j < 4; ++j)
            tile[(t4 * 4 + j) * 72 + c] = (bf16)v[j];
    }
    __syncthreads();

    int c8 = tid & 7, tl = tid >> 3;                // 32 t x 8 chunks of 8c
    bf16* dst = xT + ((size_t)b * TROWS + TPF + (size_t)tb * 128) * (NJ * CIN_)
                   + cb * 64;
    #pragma unroll
    for (int p = 0; p < 4; ++p) {
        int t = p * 32 + tl;
        *(bf16x8*)(dst + (size_t)t * (NJ * CIN_) + c8 * 8) =
            *(const bf16x8*)(tile + t * 72 + c8 * 8);
    }
}

// ---------------------------------------------------------------------------
// skconv3: fully LDS-resident inner loop.
//   block = 128 threads (2 waves); wave computes 32 cout x 64 t (acc[2][4]).
//   x tile [144][128] bf16 staged once (source-side XOR swizzle, round-1).
//   weights staged per-tap into LDS, double-buffered, linear copy of the
//   pre-swizzled Wp; one __syncthreads per tap (drains vmcnt for prefetch).
//   LDS = 36864 + 16384 = 53248 B -> 3 blocks/CU.
// ---------------------------------------------------------------------------
__global__ __launch_bounds__(128, 2) void skconv3(const bf16* __restrict__ xT,
                                                  const bf16* __restrict__ Wp,
                                                  const float* __restrict__ bias,
                                                  float* __restrict__ out) {
    __shared__ __align__(16) bf16 xs[ROWS_ST * 128];   // 36864 B
    __shared__ __align__(16) bf16 wl[2 * 32 * 128];    // 16384 B, 2 tap bufs

    const int tid  = threadIdx.x;
    const int lane = tid & 63;
    const int wave = tid >> 6;          // 0..1
    const int t0   = blockIdx.x * TT;
    const int g    = blockIdx.y;
    const int b    = blockIdx.z;

    const int lr = lane >> 4;           // row within 4-row (1KB) chunk
    const int lc = lane & 15;           // 16B chunk within row

    // ---- stage x tile: 36 wave-loads (18 per wave), 4 rows (1KB) each
    {
        const char* srcbase = (const char*)xT
            + ((size_t)b * TROWS + (size_t)(t0 + 1)) * XROW_B
            + (long)(2 * g - 1) * 64;
        #pragma unroll
        for (int j = 0; j < 18; ++j) {
            int i    = wave * 18 + j;
            int row  = 4 * i + lr;
            int chnk = lc ^ (row & 7);          // pre-swizzled source
            const char* src = srcbase + (size_t)row * XROW_B + chnk * 16;
            __builtin_amdgcn_global_load_lds(
                (const __attribute__((address_space(1))) void*)src,
                (__attribute__((address_space(3))) void*)(xs + i * 512),
                16, 0, 0);
        }
    }
    // ---- stage W tap 0 into buf 0 (linear copy; swizzle baked in Wp)
    const char* wsrc = (const char*)Wp + (size_t)g * (KT * WTAP_B);
    #pragma unroll
    for (int j = 0; j < 4; ++j) {
        int i = wave * 4 + j;
        __builtin_amdgcn_global_load_lds(
            (const __attribute__((address_space(1))) void*)(wsrc + i * 1024 + lane * 16),
            (__attribute__((address_space(3))) void*)(wl + i * 512),
            16, 0, 0);
    }
    __syncthreads();

    const int r    = lane & 15;
    const int q    = lane >> 4;
    const int woff = wave * 64;         // wave's 64-t strip

    f32x4 acc[2][4] = {};               // [cout-half][t-quarter]

    #pragma unroll
    for (int k = 0; k < KT; ++k) {
        // prefetch tap k+1 into the other buffer (fire-and-forget; the
        // end-of-tap __syncthreads drains vmcnt before it's read)
        if (k + 1 < KT) {
            const char* wk1 = wsrc + (size_t)(k + 1) * WTAP_B;
            bf16* wdst = wl + ((k + 1) & 1) * 4096;
            #pragma unroll
            for (int j = 0; j < 4; ++j) {
                int i = wave * 4 + j;
                __builtin_amdgcn_global_load_lds(
                    (const __attribute__((address_space(1))) void*)(wk1 + i * 1024 + lane * 16),
                    (__attribute__((address_space(3))) void*)(wdst + i * 512),
                    16, 0, 0);
            }
        }
        const bf16* wb   = wl + (k & 1) * 4096;
        const int   sa   = r & 7;               // weight-row swizzle key
        const int   sb_  = (r + k) & 7;         // x-row swizzle key
        const bf16* xrow = xs + (woff + r + k) * 128;
        #pragma unroll
        for (int cc = 0; cc < 4; ++cc) {
            const int cbase = q + 4 * cc;
            const bf16* ap = wb + r * 128 + ((cbase ^ sa) * 8);
            bf16x8 a0 = *(const bf16x8*)ap;
            bf16x8 a1 = *(const bf16x8*)(ap + 16 * 128);
            const bf16* bp = xrow + ((cbase ^ sb_) * 8);
            bf16x8 b0 = *(const bf16x8*)bp;
            bf16x8 b1 = *(const bf16x8*)(bp + 16 * 128);
            bf16x8 b2 = *(const bf16x8*)(bp + 32 * 128);
            bf16x8 b3 = *(const bf16x8*)(bp + 48 * 128);
            acc[0][0] = __builtin_amdgcn_mfma_f32_16x16x32_bf16(a0, b0, acc[0][0], 0, 0, 0);
            acc[1][0] = __builtin_amdgcn_mfma_f32_16x16x32_bf16(a1, b0, acc[1][0], 0, 0, 0);
            acc[0][1] = __builtin_amdgcn_mfma_f32_16x16x32_bf16(a0, b1, acc[0][1], 0, 0, 0);
            acc[1][1] = __builtin_amdgcn_mfma_f32_16x16x32_bf16(a1, b1, acc[1][1], 0, 0, 0);
            acc[0][2] = __builtin_amdgcn_mfma_f32_16x16x32_bf16(a0, b2, acc[0][2], 0, 0, 0);
            acc[1][2] = __builtin_amdgcn_mfma_f32_16x16x32_bf16(a1, b2, acc[1][2], 0, 0, 0);
            acc[0][3] = __builtin_amdgcn_mfma_f32_16x16x32_bf16(a0, b3, acc[0][3], 0, 0, 0);
            acc[1][3] = __builtin_amdgcn_mfma_f32_16x16x32_bf16(a1, b3, acc[1][3], 0, 0, 0);
        }
        __syncthreads();   // readers done with wb; prefetch (k+1) drained
    }

    // ---- epilogue: pooled bias + LeakyReLU(0.2), store fp32
    float* ob = out + (size_t)b * (NG * COUT_) * T_;
    #pragma unroll
    for (int mt = 0; mt < 2; ++mt) {
        #pragma unroll
        for (int reg = 0; reg < 4; ++reg) {
            int cout = mt * 16 + q * 4 + reg;
            float bp = 0.5f * (bias[(2 * g) * 32 + cout] +
                               bias[(2 * g + 1) * 32 + cout]);
            #pragma unroll
            for (int nt = 0; nt < 4; ++nt) {
                float v = acc[mt][nt][reg] + bp;
                v = (v >= 0.f) ? v : 0.2f * v;
                ob[(size_t)(g * COUT_ + cout) * T_ + (t0 + woff + nt * 16 + r)] = v;
            }
        }
    }
}

// ---------------------------------------------------------------------------
// Fallback (round-0 proven kernel) if workspace is too small for xT
// ---------------------------------------------------------------------------
__global__ __launch_bounds__(256) void skconv_fb(const float* __restrict__ x,
                                                 const bf16* __restrict__ Wp,
                                                 const float* __restrict__ bias,
                                                 float* __restrict__ out) {
    __shared__ __align__(16) bf16 xs[ROWS * PITCH];

    const int tid = threadIdx.x;
    const int t0  = blockIdx.x * TT;
    const int g   = blockIdx.y;
    const int b   = blockIdx.z;

    const int cbase = (2 * g - 1) * 32;
    const float* xb = x + (size_t)b * (NJ * CIN_) * T_;
    #pragma unroll
    for (int it = 0; it < (KC * ROWS) / 256; ++it) {
        int idx = tid + it * 256;
        int c   = idx / ROWS;
        int tl  = idx - c * ROWS;
        int gtt = t0 - PAD_ + tl;
        int gc  = cbase + c;
        float v = 0.f;
        if (gtt >= 0 && gtt < T_ && gc >= 0 && gc < NJ * CIN_)
            v = xb[gc * T_ + gtt];
        xs[tl * PITCH + c] = (bf16)v;
    }
    __syncthreads();

    const int lane = tid & 63;
    const int wave = tid >> 6;
    const int r    = lane & 15;
    const int q    = lane >> 4;
    const int woff = wave * 32;
    const int qo   = q * 8;

    f32x4 acc[2][2] = {};
    const bf16* wg = Wp + (size_t)g * (KT * 32 * 128);
    for (int k = 0; k < KT; ++k) {
        const bf16* wr0   = wg + k * (32 * 128) + r * 128 + qo;
        const bf16* wr1   = wr0 + 16 * 128;
        const bf16* xrow0 = xs + (woff + r + k) * PITCH + qo;
        const bf16* xrow1 = xrow0 + 16 * PITCH;
        #pragma unroll
        for (int cc = 0; cc < 4; ++cc) {
            bf16x8 a0 = *(const bf16x8*)(wr0 + cc * 32);
            bf16x8 a1 = *(const bf16x8*)(wr1 + cc * 32);
            bf16x8 b0 = *(const bf16x8*)(xrow0 + cc * 32);
            bf16x8 b1 = *(const bf16x8*)(xrow1 + cc * 32);
            acc[0][0] = __builtin_amdgcn_mfma_f32_16x16x32_bf16(a0, b0, acc[0][0], 0, 0, 0);
            acc[0][1] = __builtin_amdgcn_mfma_f32_16x16x32_bf16(a0, b1, acc[0][1], 0, 0, 0);
            acc[1][0] = __builtin_amdgcn_mfma_f32_16x16x32_bf16(a1, b0, acc[1][0], 0, 0, 0);
            acc[1][1] = __builtin_amdgcn_mfma_f32_16x16x32_bf16(a1, b1, acc[1][1], 0, 0, 0);
        }
    }

    float* ob = out + (size_t)b * (NG * COUT_) * T_;
    #pragma unroll
    for (int mt = 0; mt < 2; ++mt) {
        #pragma unroll
        for (int reg = 0; reg < 4; ++reg) {
            int cout = mt * 16 + q * 4 + reg;
            float bp = 0.5f * (bias[(2 * g) * 32 + cout] +
                               bias[(2 * g + 1) * 32 + cout]);
            #pragma unroll
            for (int nt = 0; nt < 2; ++nt) {
                float v = acc[mt][nt][reg] + bp;
                v = (v >= 0.f) ? v : 0.2f * v;
                ob[(size_t)(g * COUT_ + cout) * T_ + (t0 + woff + nt * 16 + r)] = v;
            }
        }
    }
}

// ---------------------------------------------------------------------------
extern "C" void kernel_launch(void* const* d_in, const int* in_sizes, int n_in,
                              void* d_out, int out_size, void* d_ws, size_t ws_size,
                              hipStream_t stream) {
    (void)in_sizes; (void)n_in; (void)out_size;
    const float* x    = (const float*)d_in[0];
    const float* W    = (const float*)d_in[1];
    const float* bias = (const float*)d_in[2];
    bf16* Wp   = (bf16*)d_ws;                         // 1.47 MB at offset 0
    float* out = (float*)d_out;

    const size_t xt_bytes = (size_t)NB * TROWS * (NJ * CIN_) * 2;  // ~202.5 MB
    if (ws_size >= XT_OFFSET + xt_bytes + 4096) {
        bf16* xT = (bf16*)((char*)d_ws + XT_OFFSET);
        wprep<<<dim3((NG * KT * 32 * 128) / 256), dim3(256), 0, stream>>>(W, Wp, 1);
        xpad<<<dim3(289), dim3(256), 0, stream>>>(xT);
        xprep<<<dim3(T_ / 128, NG, NB), dim3(256), 0, stream>>>(x, xT);
        skconv3<<<dim3(T_ / TT, NG, NB), dim3(128), 0, stream>>>(xT, Wp, bias, out);
    } else {
        wprep<<<dim3((NG * KT * 32 * 128) / 256), dim3(256), 0, stream>>>(W, Wp, 0);
        skconv_fb<<<dim3(T_ / TT, NG, NB), dim3(256), 0, stream>>>(x, Wp, bias, out);
    }
}